// Round 4
// baseline (349.799 us; speedup 1.0000x reference)
//
#include <hip/hip_runtime.h>

typedef __attribute__((ext_vector_type(8))) short short8;
typedef __attribute__((ext_vector_type(4))) float f32x4;
typedef __attribute__((ext_vector_type(4))) int i32x4;
typedef __attribute__((ext_vector_type(4))) unsigned short u16x4;
typedef __attribute__((ext_vector_type(2))) unsigned int u32x2;

#define B_  4
#define N_  2048
#define D_  512
#define H_  8
#define DH_ 64
#define M_  (B_ * N_)   // 8192

__device__ __forceinline__ float bf2f(unsigned short s) {
    union { unsigned u; float f; } un; un.u = ((unsigned)s) << 16; return un.f;
}
__device__ __forceinline__ unsigned short f2bf(float f) {
    union { float f; unsigned u; } un; un.f = f;
    unsigned r = un.u + 0x7FFFu + ((un.u >> 16) & 1u);
    return (unsigned short)(r >> 16);
}
// pack two fp32 -> (bf16(hi)<<16)|bf16(lo), round-half-up
__device__ __forceinline__ unsigned packbf(float lo, float hi) {
    union { float f; unsigned u; } a, b;
    a.f = lo; b.f = hi;
    return __builtin_amdgcn_perm(b.u + 0x8000u, a.u + 0x8000u, 0x07060302u);
}

typedef __attribute__((address_space(1))) const void gvoid;
typedef __attribute__((address_space(3))) void svoid;
__device__ __forceinline__ void load16_lds(const void* g, void* s) {
    __builtin_amdgcn_global_load_lds((gvoid*)g, (svoid*)s, 16, 0, 0);
}

// ---------------------------------------------------------------------------
// fp32 -> bf16 conversion
// ---------------------------------------------------------------------------
__global__ __launch_bounds__(256) void cvt_x(const float* __restrict__ src,
                                             unsigned short* __restrict__ dst) {
    const int i = (blockIdx.x * 256 + threadIdx.x) * 4;
    f32x4 v = *(const f32x4*)(src + i);
    u16x4 o;
    o[0] = f2bf(v[0]); o[1] = f2bf(v[1]); o[2] = f2bf(v[2]); o[3] = f2bf(v[3]);
    *(u16x4*)(dst + i) = o;
}

__global__ __launch_bounds__(256) void cvt_w(const float* __restrict__ W0,
                                             const float* __restrict__ W1,
                                             const float* __restrict__ W2,
                                             const float* __restrict__ W3,
                                             unsigned short* __restrict__ dst) {
    const int sel = blockIdx.y;
    const float* src = (sel == 0) ? W0 : (sel == 1) ? W1 : (sel == 2) ? W2 : W3;
    unsigned short* d = dst + (size_t)sel * D_ * D_;
    const int i = (blockIdx.x * 256 + threadIdx.x) * 4;
    f32x4 v = *(const f32x4*)(src + i);
    u16x4 o;
    o[0] = f2bf(v[0]); o[1] = f2bf(v[1]); o[2] = f2bf(v[2]); o[3] = f2bf(v[3]);
    *(u16x4*)(d + i) = o;
}

// ---------------------------------------------------------------------------
// NT GEMM with global_load_lds(16B) staging + XOR-swizzled LDS.
// out[m][n] = sum_k A[m][k]*W[n][k] + bias[n]; optional fused per-head LN.
// Tile 128x128, BK=32, 4 waves.
// LDS layout: elem-group (row, kg) stored at (row, kg ^ (row&3)); swizzle is
// applied to the GLOBAL address so the wave-uniform base + lane*16 rule holds.
// ---------------------------------------------------------------------------
template <bool F32OUT, bool LNF>
__global__ __launch_bounds__(256, 2) void gemm_nt(
    const unsigned short* __restrict__ A,
    const unsigned short* __restrict__ W,     // [nsel][512][512]
    const float* __restrict__ Bv0,
    const float* __restrict__ Bv1,
    const float* __restrict__ Bv2,
    const float* __restrict__ g0, const float* __restrict__ be0,
    const float* __restrict__ g1, const float* __restrict__ be1,
    unsigned short* __restrict__ outb,
    float* __restrict__ outf)
{
    const int mt = blockIdx.x;
    const int nt = blockIdx.y;
    const int sel = nt >> 2;
    const unsigned short* Wp = W + (size_t)sel * D_ * D_;
    const float* Bv = (sel == 0) ? Bv0 : (sel == 1) ? Bv1 : Bv2;
    const int n0 = (nt & 3) * 128;

    __shared__ __align__(16) unsigned short As[128 * 32];
    __shared__ __align__(16) unsigned short Bs[128 * 32];

    const int tid = threadIdx.x;
    const int w   = tid >> 6;
    const int l   = tid & 63;
    const int l15 = l & 15;
    const int qd  = l >> 4;
    const int wr  = w >> 1;
    const int wc  = w & 1;

    // staging map: call c -> group g=(w*2+c)*64+l ; row=g>>2 ; stored kg=g&3
    // logical kg = (g&3)^(row&3)  (so LDS holds (row, kg^(row&3)))
    int srow[2], scol[2];
#pragma unroll
    for (int c = 0; c < 2; ++c) {
        const int g   = (w * 2 + c) * 64 + l;
        const int row = g >> 2;
        srow[c] = row;
        scol[c] = ((g & 3) ^ (row & 3)) * 8;
    }

    f32x4 acc[4][4];
#pragma unroll
    for (int i = 0; i < 4; ++i)
#pragma unroll
        for (int j = 0; j < 4; ++j)
            acc[i][j] = (f32x4){0.f, 0.f, 0.f, 0.f};

    const int swz = qd ^ (l15 & 3);   // frag-read group index after swizzle

    for (int k0 = 0; k0 < D_; k0 += 32) {
        __syncthreads();
#pragma unroll
        for (int c = 0; c < 2; ++c) {
            load16_lds(A  + (size_t)(mt * 128 + srow[c]) * D_ + k0 + scol[c],
                       As + (w * 2 + c) * 512);
            load16_lds(Wp + (size_t)(n0 + srow[c]) * D_ + k0 + scol[c],
                       Bs + (w * 2 + c) * 512);
        }
        __syncthreads();

        short8 af[4], bfr[4];
#pragma unroll
        for (int rt = 0; rt < 4; ++rt)
            af[rt] = *(const short8*)&As[(wr * 64 + rt * 16 + l15) * 32 + swz * 8];
#pragma unroll
        for (int ct = 0; ct < 4; ++ct)
            bfr[ct] = *(const short8*)&Bs[(wc * 64 + ct * 16 + l15) * 32 + swz * 8];
#pragma unroll
        for (int rt = 0; rt < 4; ++rt)
#pragma unroll
            for (int ct = 0; ct < 4; ++ct)
                acc[rt][ct] = __builtin_amdgcn_mfma_f32_16x16x32_bf16(
                    af[rt], bfr[ct], acc[rt][ct], 0, 0, 0);
    }

    // epilogue: bias (+ optional fused per-head LN), write
    const float* gam = (sel == 0) ? g0 : g1;
    const float* bet = (sel == 0) ? be0 : be1;
    float gv[4], bv2[4];
    if (LNF) {
#pragma unroll
        for (int ct = 0; ct < 4; ++ct) { gv[ct] = gam[ct * 16 + l15]; bv2[ct] = bet[ct * 16 + l15]; }
    }

#pragma unroll
    for (int rt = 0; rt < 4; ++rt) {
        float v[4][4];   // [ct][r]
#pragma unroll
        for (int ct = 0; ct < 4; ++ct) {
            const float bias = Bv[n0 + wc * 64 + ct * 16 + l15];
#pragma unroll
            for (int r = 0; r < 4; ++r) v[ct][r] = acc[rt][ct][r] + bias;
        }
        if (LNF && sel < 2) {
#pragma unroll
            for (int r = 0; r < 4; ++r) {
                float s  = v[0][r] + v[1][r] + v[2][r] + v[3][r];
                float s2 = v[0][r]*v[0][r] + v[1][r]*v[1][r] + v[2][r]*v[2][r] + v[3][r]*v[3][r];
#pragma unroll
                for (int o = 1; o <= 8; o <<= 1) {
                    s  += __shfl_xor(s, o);
                    s2 += __shfl_xor(s2, o);
                }
                const float mu  = s * 0.015625f;
                const float var = s2 * 0.015625f - mu * mu;
                const float rs  = rsqrtf(var + 1e-6f);
#pragma unroll
                for (int ct = 0; ct < 4; ++ct)
                    v[ct][r] = (v[ct][r] - mu) * rs * gv[ct] + bv2[ct];
            }
        }
#pragma unroll
        for (int ct = 0; ct < 4; ++ct) {
            const int col  = n0 + wc * 64 + ct * 16 + l15;
            const int row0 = mt * 128 + wr * 64 + rt * 16 + qd * 4;
#pragma unroll
            for (int r = 0; r < 4; ++r) {
                const size_t oidx = (size_t)(row0 + r) * D_ + col;
                if (F32OUT) outf[oidx] = v[ct][r];
                else        outb[(size_t)sel * M_ * D_ + oidx] = f2bf(v[ct][r]);
            }
        }
    }
}

// ---------------------------------------------------------------------------
// V transpose: V[b*2048+n][dh512] -> Vt[b][dh512][n2048]
// ---------------------------------------------------------------------------
__global__ __launch_bounds__(256) void transpose_v(
    const unsigned short* __restrict__ V, unsigned short* __restrict__ Vt)
{
    const int nt = blockIdx.x;
    const int dt = blockIdx.y;
    const int b  = blockIdx.z;
    __shared__ __align__(16) unsigned short T[64][72];
    const int t = threadIdx.x;

#pragma unroll
    for (int half = 0; half < 2; ++half) {
        const int n = half * 32 + (t >> 3);
        const int c = (t & 7) * 8;
        short8 v = *(const short8*)(V + (size_t)(b * N_ + nt * 64 + n) * D_ + dt * 64 + c);
#pragma unroll
        for (int j = 0; j < 8; ++j) T[c + j][n] = (unsigned short)v[j];
    }
    __syncthreads();
    const int dh = t >> 2, p = t & 3;
    i32x4 a0 = *(const i32x4*)&T[dh][p * 16];
    i32x4 a1 = *(const i32x4*)&T[dh][p * 16 + 8];
    unsigned short* dst = Vt + ((size_t)b * D_ + dt * 64 + dh) * N_ + nt * 64 + p * 16;
    *(i32x4*)dst       = a0;
    *(i32x4*)(dst + 8) = a1;
}

// ---------------------------------------------------------------------------
// attn3: one wave = one head, 32 q-rows; kv-tile 64; register-double-buffered
// K and bias (one iteration ahead), V issued at iteration top; packed-bf16 P.
// S^T = K Q^T, O^T = V^T P^T; wave-private LDS for P; no barriers.
// ---------------------------------------------------------------------------
#define ATTN_STEP(KF_C, BB_C, KF_N, BB_N, KT)                                       \
  {                                                                                 \
    const int kv0 = (KT) * 64;                                                      \
    const int kvn = ((KT) < 31) ? kv0 + 64 : kv0;                                   \
    short8 vf[4][2];                                                                \
    _Pragma("unroll") for (int rt = 0; rt < 4; ++rt)                                \
      _Pragma("unroll") for (int hf = 0; hf < 2; ++hf)                              \
        vf[rt][hf] = *(const short8*)(vb_ + (size_t)(rt*16+l15)*N_ + kv0 + hf*32 + qd*8); \
    _Pragma("unroll") for (int rt = 0; rt < 4; ++rt)                                \
      _Pragma("unroll") for (int hf = 0; hf < 2; ++hf)                              \
        KF_N[rt][hf] = *(const short8*)(kb_ + (size_t)(kvn + rt*16+l15)*D_ + hf*32 + qd*8); \
    _Pragma("unroll") for (int rt = 0; rt < 4; ++rt)                                \
      _Pragma("unroll") for (int ct = 0; ct < 2; ++ct)                              \
        BB_N[rt][ct] = *(const f32x4*)(bb_ + (size_t)(ct*16+l15)*N_ + kvn + rt*16 + qd*4); \
    f32x4 St[4][2];                                                                 \
    _Pragma("unroll") for (int rt = 0; rt < 4; ++rt)                                \
      _Pragma("unroll") for (int ct = 0; ct < 2; ++ct) {                            \
        f32x4 s = (f32x4){0.f, 0.f, 0.f, 0.f};                                      \
        s = __builtin_amdgcn_mfma_f32_16x16x32_bf16(KF_C[rt][0], qf[ct][0], s, 0, 0, 0); \
        s = __builtin_amdgcn_mfma_f32_16x16x32_bf16(KF_C[rt][1], qf[ct][1], s, 0, 0, 0); \
        St[rt][ct] = s;                                                             \
      }                                                                             \
    _Pragma("unroll") for (int ct = 0; ct < 2; ++ct) {                              \
      float sv[4][4];                                                               \
      float mx = -3.0e38f;                                                          \
      _Pragma("unroll") for (int rt = 0; rt < 4; ++rt)                              \
        _Pragma("unroll") for (int r = 0; r < 4; ++r) {                             \
          const float xv = St[rt][ct][r] * 0.125f + BB_C[rt][ct][r];                \
          sv[rt][r] = xv; mx = fmaxf(mx, xv);                                       \
        }                                                                           \
      mx = fmaxf(mx, __shfl_xor(mx, 16));                                           \
      mx = fmaxf(mx, __shfl_xor(mx, 32));                                           \
      const float mnew  = fmaxf(m_i[ct], mx);                                       \
      const float alpha = __expf(m_i[ct] - mnew);                                   \
      float rsum = 0.f;                                                             \
      _Pragma("unroll") for (int rt = 0; rt < 4; ++rt) {                            \
        const float p0 = __expf(sv[rt][0] - mnew), p1 = __expf(sv[rt][1] - mnew);   \
        const float p2 = __expf(sv[rt][2] - mnew), p3 = __expf(sv[rt][3] - mnew);   \
        rsum += (p0 + p1) + (p2 + p3);                                              \
        u32x2 pw; pw[0] = packbf(p0, p1); pw[1] = packbf(p2, p3);                   \
        *(u32x2*)&Pw[w][ct*16 + l15][rt*16 + qd*4] = pw;                            \
      }                                                                             \
      rsum += __shfl_xor(rsum, 16);                                                 \
      rsum += __shfl_xor(rsum, 32);                                                 \
      l_i[ct] = l_i[ct] * alpha + rsum;                                             \
      m_i[ct] = mnew;                                                               \
      _Pragma("unroll") for (int rt = 0; rt < 4; ++rt)                              \
        _Pragma("unroll") for (int r = 0; r < 4; ++r)                               \
          Ot[rt][ct][r] *= alpha;                                                   \
    }                                                                               \
    short8 pf[2][2];                                                                \
    _Pragma("unroll") for (int ct = 0; ct < 2; ++ct)                                \
      _Pragma("unroll") for (int hf = 0; hf < 2; ++hf)                              \
        pf[ct][hf] = *(const short8*)&Pw[w][ct*16 + l15][hf*32 + qd*8];             \
    _Pragma("unroll") for (int rt = 0; rt < 4; ++rt)                                \
      _Pragma("unroll") for (int ct = 0; ct < 2; ++ct) {                            \
        Ot[rt][ct] = __builtin_amdgcn_mfma_f32_16x16x32_bf16(vf[rt][0], pf[ct][0], Ot[rt][ct], 0, 0, 0); \
        Ot[rt][ct] = __builtin_amdgcn_mfma_f32_16x16x32_bf16(vf[rt][1], pf[ct][1], Ot[rt][ct], 0, 0, 0); \
      }                                                                             \
  }

__global__ __launch_bounds__(256, 2) void attn3(
    const unsigned short* __restrict__ Qm,
    const unsigned short* __restrict__ Km,
    const unsigned short* __restrict__ Vt,
    const float* __restrict__ bias,
    unsigned short* __restrict__ AO)
{
    const int hg = blockIdx.x;   // 0..1
    const int qt = blockIdx.y;   // 0..63
    const int b  = blockIdx.z;   // 0..3
    const int w  = threadIdx.x >> 6;
    const int h  = hg * 4 + w;
    const int l  = threadIdx.x & 63;
    const int l15 = l & 15;
    const int qd  = l >> 4;
    const int q0 = qt * 32;

    __shared__ __align__(16) unsigned short Pw[4][32][72];

    short8 qf[2][2];
#pragma unroll
    for (int ct = 0; ct < 2; ++ct)
#pragma unroll
        for (int hf = 0; hf < 2; ++hf)
            qf[ct][hf] = *(const short8*)(Qm +
                (size_t)(b * N_ + q0 + ct * 16 + l15) * D_ + h * DH_ + hf * 32 + qd * 8);

    f32x4 Ot[4][2];
#pragma unroll
    for (int rt = 0; rt < 4; ++rt)
#pragma unroll
        for (int ct = 0; ct < 2; ++ct) Ot[rt][ct] = (f32x4){0.f, 0.f, 0.f, 0.f};
    float m_i[2] = {-3.0e38f, -3.0e38f};
    float l_i[2] = {0.f, 0.f};

    const unsigned short* kb_ = Km + (size_t)b * N_ * D_ + h * DH_;
    const unsigned short* vb_ = Vt + ((size_t)b * D_ + h * DH_) * N_;
    const float* bb_ = bias + (size_t)b * N_ * N_ + (size_t)q0 * N_;

    short8 kfA[4][2], kfB[4][2];
    f32x4  bbA[4][2], bbB[4][2];

    // preload tile 0 into A-buffers
#pragma unroll
    for (int rt = 0; rt < 4; ++rt)
#pragma unroll
        for (int hf = 0; hf < 2; ++hf)
            kfA[rt][hf] = *(const short8*)(kb_ + (size_t)(rt * 16 + l15) * D_ + hf * 32 + qd * 8);
#pragma unroll
    for (int rt = 0; rt < 4; ++rt)
#pragma unroll
        for (int ct = 0; ct < 2; ++ct)
            bbA[rt][ct] = *(const f32x4*)(bb_ + (size_t)(ct * 16 + l15) * N_ + rt * 16 + qd * 4);

    for (int kt2 = 0; kt2 < 16; ++kt2) {
        ATTN_STEP(kfA, bbA, kfB, bbB, 2 * kt2);
        ATTN_STEP(kfB, bbB, kfA, bbA, 2 * kt2 + 1);
    }

    // epilogue: O^T frag: row=dh(rt*16+qd*4+r), col=q(ct*16+l15)
#pragma unroll
    for (int ct = 0; ct < 2; ++ct) {
        const float inv = 1.f / l_i[ct];
        const int q = q0 + ct * 16 + l15;
#pragma unroll
        for (int rt = 0; rt < 4; ++rt) {
            u16x4 ob;
#pragma unroll
            for (int r = 0; r < 4; ++r) ob[r] = f2bf(Ot[rt][ct][r] * inv);
            *(u16x4*)(AO + (size_t)(b * N_ + q) * D_ + h * DH_ + rt * 16 + qd * 4) = ob;
        }
    }
}

// ---------------------------------------------------------------------------
extern "C" void kernel_launch(void* const* d_in, const int* in_sizes, int n_in,
                              void* d_out, int out_size, void* d_ws, size_t ws_size,
                              hipStream_t stream) {
    const float* x  = (const float*)d_in[0];
    const float* ab = (const float*)d_in[1];
    const float* Wq = (const float*)d_in[2];
    const float* bq = (const float*)d_in[3];
    const float* Wk = (const float*)d_in[4];
    const float* bk = (const float*)d_in[5];
    const float* Wv = (const float*)d_in[6];
    const float* bv = (const float*)d_in[7];
    const float* Wo = (const float*)d_in[8];
    const float* bo = (const float*)d_in[9];
    const float* qg = (const float*)d_in[10];
    const float* qb = (const float*)d_in[11];
    const float* kg = (const float*)d_in[12];
    const float* kb = (const float*)d_in[13];

    // ws layout (bf16 elements)
    unsigned short* xb = (unsigned short*)d_ws;                 // [8192][512]
    unsigned short* Wb = xb + (size_t)M_ * D_;                  // [4][512][512] q,k,v,o
    unsigned short* Y  = Wb + (size_t)4 * D_ * D_;              // [3][8192][512]
    unsigned short* Vt = Y  + (size_t)3 * M_ * D_;              // [4][512][2048]
    unsigned short* AO = Vt + (size_t)M_ * D_;                  // [8192][512]
    float* out = (float*)d_out;

    cvt_x<<<dim3(M_ * D_ / 1024), dim3(256), 0, stream>>>(x, xb);
    cvt_w<<<dim3(D_ * D_ / 1024, 4), dim3(256), 0, stream>>>(Wq, Wk, Wv, Wo, Wb);

    // QKV projection with fused per-head LN on q,k
    gemm_nt<false, true><<<dim3(64, 12), dim3(256), 0, stream>>>(
        xb, Wb, bq, bk, bv, qg, qb, kg, kb, Y, nullptr);

    // V -> V^T
    transpose_v<<<dim3(32, 8, 4), dim3(256), 0, stream>>>(
        Y + (size_t)2 * M_ * D_, Vt);

    // attention
    attn3<<<dim3(2, 64, 4), dim3(256), 0, stream>>>(
        Y, Y + (size_t)M_ * D_, Vt, ab, AO);

    // output projection -> d_out (fp32)
    gemm_nt<true, false><<<dim3(64, 4), dim3(256), 0, stream>>>(
        AO, Wb + (size_t)3 * D_ * D_, bo, bo, bo,
        nullptr, nullptr, nullptr, nullptr, nullptr, out);
}